// Round 1
// baseline (926.154 us; speedup 1.0000x reference)
//
#include <hip/hip_runtime.h>
#include <hip/hip_bf16.h>
#include <cmath>

#define D_    1024
#define B_    128
#define N_    576
#define ROWS_ (B_*N_)
#define TWOD_ 2048
#define TAU_  1e-5f
#define NU_   8

__device__ __forceinline__ float waveReduceSum(float v){
  #pragma unroll
  for (int m=32;m;m>>=1) v += __shfl_xor(v,m,64);
  return v;
}
__device__ __forceinline__ float waveReduceMax(float v){
  #pragma unroll
  for (int m=32;m;m>>=1) v = fmaxf(v,__shfl_xor(v,m,64));
  return v;
}

// zero wimg, p_corr, count
__global__ __launch_bounds__(256) void k_init(float* wimg, float* p_corr, int* count){
  int i = blockIdx.x*256 + threadIdx.x;
  if (i < B_*D_) wimg[i] = 0.f;
  if (i < ROWS_) p_corr[i] = 0.f;
  if (i == 0) *count = 0;
}

// t_emb = pe[timesteps]
__global__ __launch_bounds__(256) void k_temb(const int* __restrict__ ts, float* __restrict__ temb){
  int b = blockIdx.x;
  float t = (float)ts[b];
  for (int i=threadIdx.x; i<D_/2; i+=256){
    float dv = expf((float)(2*i) * (-9.210340371976184f/(float)D_));
    float a = t*dv;
    temb[b*D_ + 2*i]   = sinf(a);
    temb[b*D_ + 2*i+1] = cosf(a);
  }
}

// C[128,nout] = act((A (+A2)) [128,1024] @ W + bias)
// tmode==0: W is [1024,nout] row-major, read W[k*ldw+col]   (standard)
// tmode==1: W is [nout,1024] row-major, read W[col*ldw+k]   (transposed access, A@W^T)
// act: 0=none 1=silu.
// grid (nout/128, 64), block 256: 2 rows x 128 cols per block, 1 output per thread.
// 512 blocks (1024 for nout=2048) -> 2+ blocks/CU vs old 1: latency hiding.
__global__ __launch_bounds__(256) void k_gemm(const float* __restrict__ A, const float* __restrict__ A2,
    const float* __restrict__ W, int ldw, const float* __restrict__ bias, float* __restrict__ C,
    int nout, int act, int tmode){
  __shared__ float a_s[2][D_];
  int r0 = blockIdx.y*2;
  const float4* A4 = (const float4*)(A + (size_t)r0*D_);
  float4* s4 = (float4*)a_s;
  if (A2){
    const float4* B4 = (const float4*)(A2 + (size_t)r0*D_);
    for (int i=threadIdx.x;i<512;i+=256){
      float4 a = A4[i], b = B4[i];
      s4[i] = make_float4(a.x+b.x, a.y+b.y, a.z+b.z, a.w+b.w);
    }
  } else {
    for (int i=threadIdx.x;i<512;i+=256) s4[i] = A4[i];
  }
  __syncthreads();
  int rsel = threadIdx.x>>7;                 // 0..1
  int row  = r0 + rsel;
  int col  = blockIdx.x*128 + (threadIdx.x&127);
  const float* arow = a_s[rsel];
  float acc0=0.f, acc1=0.f;                  // two chains: break fma dependency
  if (tmode==0){
    const float* wp = W + col;
    #pragma unroll 8
    for (int k=0;k<D_;k+=2){
      acc0 = fmaf(arow[k],   wp[(size_t)k*ldw],       acc0);
      acc1 = fmaf(arow[k+1], wp[(size_t)(k+1)*ldw],   acc1);
    }
  } else {
    const float* wp = W + (size_t)col*ldw;
    #pragma unroll 4
    for (int k=0;k<D_;k+=4){
      float4 wv = *(const float4*)(wp+k);
      acc0 = fmaf(arow[k],  wv.x,acc0); acc1 = fmaf(arow[k+1],wv.y,acc1);
      acc0 = fmaf(arow[k+2],wv.z,acc0); acc1 = fmaf(arow[k+3],wv.w,acc1);
    }
  }
  float o = acc0 + acc1 + (bias ? bias[col] : 0.f);
  if (act==1) o = o/(1.f+expf(-o));
  C[(size_t)row*nout+col]=o;
}

// s[row] = text[b] . imgf[row]   (one wave per row; D=1024 floats = 256 float4)
__global__ __launch_bounds__(256) void k_dots(const float* __restrict__ text,
    const float* __restrict__ imgf, float* __restrict__ s){
  int wave = threadIdx.x>>6, lane = threadIdx.x&63;
  int row = blockIdx.x*4 + wave;
  int b = row / N_;
  const float4* ip = (const float4*)(imgf + (size_t)row*D_);
  const float4* tp = (const float4*)(text + (size_t)b*D_);
  float acc=0.f;
  #pragma unroll
  for (int p=0;p<4;p++){
    float4 a = ip[p*64+lane];
    float4 t = tp[p*64+lane];
    acc = fmaf(a.x,t.x,acc); acc = fmaf(a.y,t.y,acc);
    acc = fmaf(a.z,t.z,acc); acc = fmaf(a.w,t.w,acc);
  }
  acc = waveReduceSum(acc);
  if (lane==0) s[row]=acc;
}

// per-b softmax over N_; optionally append entries with w>TAU to list
__global__ __launch_bounds__(256) void k_softmax(const float* __restrict__ s, float* __restrict__ w,
    int buildList, int* count, int* lrow, float* liw){
  int b = blockIdx.x;
  __shared__ float rbuf[4];
  const float* sp = s + b*N_;
  float m = -3e38f;
  for (int i=threadIdx.x;i<N_;i+=256) m = fmaxf(m, sp[i]);
  m = waveReduceMax(m);
  if ((threadIdx.x&63)==0) rbuf[threadIdx.x>>6]=m;
  __syncthreads();
  m = fmaxf(fmaxf(rbuf[0],rbuf[1]),fmaxf(rbuf[2],rbuf[3]));
  __syncthreads();
  float sum=0.f;
  for (int i=threadIdx.x;i<N_;i+=256) sum += expf(sp[i]-m);
  sum = waveReduceSum(sum);
  if ((threadIdx.x&63)==0) rbuf[threadIdx.x>>6]=sum;
  __syncthreads();
  sum = rbuf[0]+rbuf[1]+rbuf[2]+rbuf[3];
  float inv = 1.f/sum;
  float* wp = w + b*N_;
  for (int i=threadIdx.x;i<N_;i+=256){
    float wi = expf(sp[i]-m)*inv;
    wp[i]=wi;
    if (buildList && wi > TAU_){
      int pos = atomicAdd(count,1);
      if (pos < ROWS_){ lrow[pos]=b*N_+i; liw[pos]=wi; }
    }
  }
}

__global__ __launch_bounds__(256) void k_lbase(const float* __restrict__ x, float* __restrict__ s){
  int i = blockIdx.x*256+threadIdx.x;
  ((float4*)s)[i] = ((const float4*)x)[i];
}

// listed rows: s[row] = x[row] + iw * (imgf[row] . kq[b])
__global__ __launch_bounds__(256) void k_lsparse(const float* __restrict__ x, const float* __restrict__ imgf,
    const float* __restrict__ kq, const int* __restrict__ count, const int* __restrict__ lrow,
    const float* __restrict__ liw, float* __restrict__ s){
  int wave=threadIdx.x>>6, lane=threadIdx.x&63;
  int cnt = min(*count, ROWS_);
  for (int e = blockIdx.x*4+wave; e<cnt; e += gridDim.x*4){
    int row=lrow[e], b=row/N_; float iw=liw[e];
    const float4* ip=(const float4*)(imgf+(size_t)row*D_);
    const float4* kp=(const float4*)(kq + b*D_);
    float acc=0.f;
    #pragma unroll
    for (int p=0;p<4;p++){
      int c = p*64+lane;
      float4 a = ip[c];
      float4 k = kp[c];
      acc = fmaf(a.x,k.x,acc); acc = fmaf(a.y,k.y,acc);
      acc = fmaf(a.z,k.z,acc); acc = fmaf(a.w,k.w,acc);
    }
    acc = waveReduceSum(acc);
    if (lane==0) s[row] = x[row] + iw*acc;
  }
}

// wimg[b,:] += (weight[row]*iw) * imgf[row,:] over listed rows
__global__ __launch_bounds__(256) void k_wimg(const float* __restrict__ imgf, const float* __restrict__ wgt,
    const int* __restrict__ count, const int* __restrict__ lrow,
    const float* __restrict__ liw, float* __restrict__ wimg){
  int cnt = min(*count, ROWS_);
  for (int e = blockIdx.x; e<cnt; e += gridDim.x){
    int row=lrow[e], b=row/N_;
    float coef = liw[e]*wgt[row];
    const float* src = imgf + (size_t)row*D_;
    for (int i=threadIdx.x;i<D_;i+=256)
      atomicAdd(&wimg[b*D_+i], coef*src[i]);
  }
}

// p0[b] = sum_j relu(r[b,j])*wd2[j] + bd2
__global__ __launch_bounds__(256) void k_p0(const float* __restrict__ r, const float* __restrict__ wd2,
    const float* __restrict__ bd2, float* __restrict__ p0){
  __shared__ float rbuf[4];
  int b=blockIdx.x;
  float acc=0.f;
  for (int j=threadIdx.x;j<TWOD_;j+=256)
    acc = fmaf(fmaxf(r[b*TWOD_+j],0.f), wd2[j], acc);
  acc = waveReduceSum(acc);
  if((threadIdx.x&63)==0) rbuf[threadIdx.x>>6]=acc;
  __syncthreads();
  if (threadIdx.x==0) p0[b] = rbuf[0]+rbuf[1]+rbuf[2]+rbuf[3] + bd2[0];
}

// exact correction for listed rows:
// p_corr[row] += sum_j (relu(r[b,j]+iw*G_j) - relu(r[b,j]))*wd2[j],  G = imgf[row]@Wd1_bot
// grid (8 j-chunks of 256, NG entry groups)
__global__ __launch_bounds__(256) void k_corr(const float* __restrict__ imgf, const float* __restrict__ Wd1,
    const float* __restrict__ r, const float* __restrict__ wd2, const int* __restrict__ count,
    const int* __restrict__ lrow, const float* __restrict__ liw,
    float* __restrict__ p_corr){
  __shared__ __align__(16) float img[D_][NU_];
  __shared__ float rbuf[4];
  int j = blockIdx.x*256 + threadIdx.x;
  float wd2j = wd2[j];
  int cnt = min(*count, ROWS_);
  int NG = gridDim.y;
  for (int base = blockIdx.y*NU_; base < cnt; base += NG*NU_){
    int nu = min(NU_, cnt-base);
    __syncthreads();
    for (int u=0;u<nu;u++){
      const float* src = imgf + (size_t)lrow[base+u]*D_;
      for (int i=threadIdx.x;i<D_;i+=256) img[i][u]=src[i];
    }
    for (int u=nu;u<NU_;u++)
      for (int i=threadIdx.x;i<D_;i+=256) img[i][u]=0.f;
    __syncthreads();
    float g[NU_];
    #pragma unroll
    for (int u=0;u<NU_;u++) g[u]=0.f;
    const float* wp = Wd1 + (size_t)D_*TWOD_ + j;
    #pragma unroll 4
    for (int e=0;e<D_;e++){
      float wv = wp[(size_t)e*TWOD_];
      const float4* ir = (const float4*)(&img[e][0]);
      float4 i0 = ir[0], i1 = ir[1];
      g[0]=fmaf(i0.x,wv,g[0]); g[1]=fmaf(i0.y,wv,g[1]);
      g[2]=fmaf(i0.z,wv,g[2]); g[3]=fmaf(i0.w,wv,g[3]);
      g[4]=fmaf(i1.x,wv,g[4]); g[5]=fmaf(i1.y,wv,g[5]);
      g[6]=fmaf(i1.z,wv,g[6]); g[7]=fmaf(i1.w,wv,g[7]);
    }
    for (int u=0;u<nu;u++){
      int row = lrow[base+u];
      float rv = r[(size_t)(row/N_)*TWOD_ + j];
      float c  = rv + liw[base+u]*g[u];
      float contrib = (fmaxf(c,0.f)-fmaxf(rv,0.f))*wd2j;
      contrib = waveReduceSum(contrib);
      if ((threadIdx.x&63)==0) rbuf[threadIdx.x>>6]=contrib;
      __syncthreads();
      if (threadIdx.x==0) atomicAdd(&p_corr[row], rbuf[0]+rbuf[1]+rbuf[2]+rbuf[3]);
      __syncthreads();
    }
  }
}

__global__ __launch_bounds__(256) void k_final(const float* __restrict__ p0, const float* __restrict__ p_corr,
    const float* __restrict__ wgt, float* __restrict__ out){
  int i = blockIdx.x*256+threadIdx.x;
  if (i<ROWS_){
    int b = i/N_;
    out[i] = p0[b] + p_corr[i] + wgt[i];
  }
}

extern "C" void kernel_launch(void* const* d_in, const int* in_sizes, int n_in,
                              void* d_out, int out_size, void* d_ws, size_t ws_size,
                              hipStream_t stream) {
  const float* x    = (const float*)d_in[0];
  const int*   ts   = (const int*)  d_in[1];
  const float* text = (const float*)d_in[2];
  const float* imgf = (const float*)d_in[3];
  const float* Wq   = (const float*)d_in[4];
  const float* Wk   = (const float*)d_in[5];
  const float* Wv   = (const float*)d_in[6];
  const float* Wp   = (const float*)d_in[7];
  const float* bp   = (const float*)d_in[8];
  const float* Wt1  = (const float*)d_in[9];
  const float* bt1  = (const float*)d_in[10];
  const float* Wt2  = (const float*)d_in[11];
  const float* bt2  = (const float*)d_in[12];
  const float* Wd1  = (const float*)d_in[13];
  const float* bd1  = (const float*)d_in[14];
  const float* Wd2  = (const float*)d_in[15];
  const float* bd2  = (const float*)d_in[16];
  float* out = (float*)d_out;

  // compact workspace layout: ~4.62 MB total
  float* f = (float*)d_ws;
  float* bufA  = f;            // [131072] temb -> kq
  float* bufB  = f +  131072;  // [131072] h1 -> q -> v-out -> newemb
  float* cond  = f +  262144;  // [131072]
  float* wimg  = f +  393216;  // [131072]
  float* rbuf  = f +  524288;  // [262144]
  float* sbuf  = f +  786432;  // [73728]
  float* wgt   = f +  860160;  // [73728]
  float* pcorr = f +  933888;  // [73728]
  float* liw   = f + 1007616;  // [73728]
  int*   lrow  = (int*)(f + 1081344); // [73728]
  float* p0    = f + 1155072;  // [128]
  int*   cnt   = (int*)(f + 1155200); // [64]

  // init scratch
  k_init<<<512,256,0,stream>>>(wimg, pcorr, cnt);
  // timestep conditioning chain: temb -> silu(.@Wt1) -> .@Wt2 = cond
  k_temb<<<B_,256,0,stream>>>(ts, bufA);
  k_gemm<<<dim3(8,64),256,0,stream>>>(bufA, nullptr, Wt1, D_, bt1, bufB, D_, 1, 0);
  k_gemm<<<dim3(8,64),256,0,stream>>>(bufB, nullptr, Wt2, D_, bt2, cond, D_, 0, 0);
  // i_w logits (full image pass) + softmax + build significant list
  k_dots<<<ROWS_/4,256,0,stream>>>(text, imgf, sbuf);
  k_softmax<<<B_,256,0,stream>>>(sbuf, sbuf, 1, cnt, lrow, liw);
  // q = (text+cond)@Wq (add fused into staging) ; kq = Wk @ q (transposed-access GEMM)
  k_gemm<<<dim3(8,64),256,0,stream>>>(text, cond, Wq, D_, nullptr, bufB, D_, 0, 0);
  k_gemm<<<dim3(8,64),256,0,stream>>>(bufB, nullptr, Wk, D_, nullptr, bufA, D_, 0, 1);
  // attention logits: base x, sparse i_w*(imgf.kq) correction, softmax -> weight
  k_lbase<<<ROWS_/1024,256,0,stream>>>(x, sbuf);
  k_lsparse<<<64,256,0,stream>>>(x, imgf, bufA, cnt, lrow, liw, sbuf);
  k_softmax<<<B_,256,0,stream>>>(sbuf, wgt, 0, cnt, lrow, liw);
  // weighted image sum (sparse), then new_emb chain (wimg+cond fused into staging)
  k_wimg<<<128,256,0,stream>>>(imgf, wgt, cnt, lrow, liw, wimg);
  k_gemm<<<dim3(8,64),256,0,stream>>>(wimg, cond, Wv, D_, nullptr, bufA, D_, 0, 0);
  k_gemm<<<dim3(8,64),256,0,stream>>>(bufA, nullptr, Wp, D_, bp, bufB, D_, 0, 0);
  // r = new_emb @ Wd1_top + bd1
  k_gemm<<<dim3(16,64),256,0,stream>>>(bufB, nullptr, Wd1, TWOD_, bd1, rbuf, TWOD_, 0, 0);
  // decoder: baseline p0 per b + exact sparse correction
  k_p0<<<B_,256,0,stream>>>(rbuf, Wd2, bd2, p0);
  k_corr<<<dim3(8,64),256,0,stream>>>(imgf, Wd1, rbuf, Wd2, cnt, lrow, liw, pcorr);
  // out = p0 + corr + weight
  k_final<<<(ROWS_+255)/256,256,0,stream>>>(p0, pcorr, wgt, out);
}